// Round 8
// baseline (108.021 us; speedup 1.0000x reference)
//
#include <hip/hip_runtime.h>
#include <math.h>

// Problem shape (fixed by the reference): B=4, S=4, N=2048, D=2048
#define NB 4
#define NS 4
#define NN 2048
#define ND 2048
#define NTHREADS 512
#define SQRT_D 45.254833995939045f   // sqrt(2048)

typedef float f32x4 __attribute__((ext_vector_type(4)));

// Compaction-butterfly ship, literal indices only (R3 lesson, R5/R7-proven).
#define SHIP(I, H, M_) {                                      \
    const float keep_ = hi_ ? v[(I)+(H)] : v[(I)];            \
    const float give_ = hi_ ? v[(I)] : v[(I)+(H)];            \
    v[(I)] = keep_ + __shfl_xor(give_, (M_)); }

// 512 threads, one f32x4 chunk each; __launch_bounds__(512,8) pins VGPR<=64
// -> 8 waves/SIMD (32 waves/CU): the TLP experiment. Est. demand ~52.
__global__ __launch_bounds__(NTHREADS, 8)
void hyperconn_kernel(const float* __restrict__ residuals,
                      const float* __restrict__ gamma,
                      const float* __restrict__ w_alpha,
                      const float* __restrict__ scale_alpha,
                      const float* __restrict__ static_alpha,
                      const float* __restrict__ w_beta,
                      const float* __restrict__ scale_beta,
                      const float* __restrict__ static_beta,
                      float* __restrict__ out)
{
    __shared__ float red[8][32];   // per-wave compacted sums (idx = brev5)
    __shared__ float asb[NS][6];   // [s][0..4]=alpha row, [s][5]=beta

    const int tid  = threadIdx.x;
    const int bn   = blockIdx.x;          // 0 .. NB*NN-1
    const int b    = bn >> 11;
    const int n    = bn & (NN - 1);
    const int wave = tid >> 6;
    const int lane = tid & 63;
    const int d    = tid << 2;            // one f32x4 chunk per thread

    const size_t row_stride = (size_t)NN * ND;
    const float* xp = residuals + (size_t)(b * NS) * row_stride + (size_t)n * ND + d;
    float*       op = out       + (size_t)(b * NS) * row_stride + (size_t)n * ND + d;

    // ---- Dots in fp32 straight from global-load registers ----
    // v[s*7]=ssq(x[s]); v[s*7+1+j]=dot(x[s], w_j*(1+g)); v[28..31] pad
    float v[32];
#pragma unroll
    for (int k = 0; k < 32; ++k) v[k] = 0.f;

    {
        f32x4 x0 = *(const f32x4*)(xp);
        f32x4 x1 = *(const f32x4*)(xp + row_stride);
        f32x4 x2 = *(const f32x4*)(xp + 2 * row_stride);
        f32x4 x3 = *(const f32x4*)(xp + 3 * row_stride);
        f32x4 g4 = *(const f32x4*)(gamma + d);
#pragma unroll
        for (int e = 0; e < 4; ++e) {
            v[0]  = __builtin_fmaf(x0[e], x0[e], v[0]);
            v[7]  = __builtin_fmaf(x1[e], x1[e], v[7]);
            v[14] = __builtin_fmaf(x2[e], x2[e], v[14]);
            v[21] = __builtin_fmaf(x3[e], x3[e], v[21]);
        }
#pragma unroll
        for (int j = 0; j < 6; ++j) {
            const float* wsrc = (j < 5) ? (w_alpha + (size_t)j * ND + d)
                                        : (w_beta + d);
            f32x4 w4 = *(const f32x4*)wsrc;
            f32x4 wg = w4 + w4 * g4;       // w * (1 + gamma)
#pragma unroll
            for (int e = 0; e < 4; ++e) {
                v[1 + j]  = __builtin_fmaf(x0[e], wg[e], v[1 + j]);
                v[8 + j]  = __builtin_fmaf(x1[e], wg[e], v[8 + j]);
                v[15 + j] = __builtin_fmaf(x2[e], wg[e], v[15 + j]);
                v[22 + j] = __builtin_fmaf(x3[e], wg[e], v[22 + j]);
            }
        }
        // x0..x3 die here: re-read (L2-hot) for the apply phase.
    }

    // ---- Compaction butterfly: 31 swizzles + 1 xor32 (R5/R7-proven) ----
    { const bool hi_ = (lane & 1) != 0;
      SHIP(0,16,1)  SHIP(1,16,1)  SHIP(2,16,1)  SHIP(3,16,1)
      SHIP(4,16,1)  SHIP(5,16,1)  SHIP(6,16,1)  SHIP(7,16,1)
      SHIP(8,16,1)  SHIP(9,16,1)  SHIP(10,16,1) SHIP(11,16,1)
      SHIP(12,16,1) SHIP(13,16,1) SHIP(14,16,1) SHIP(15,16,1) }
    { const bool hi_ = (lane & 2) != 0;
      SHIP(0,8,2) SHIP(1,8,2) SHIP(2,8,2) SHIP(3,8,2)
      SHIP(4,8,2) SHIP(5,8,2) SHIP(6,8,2) SHIP(7,8,2) }
    { const bool hi_ = (lane & 4) != 0;
      SHIP(0,4,4) SHIP(1,4,4) SHIP(2,4,4) SHIP(3,4,4) }
    { const bool hi_ = (lane & 8) != 0;
      SHIP(0,2,8) SHIP(1,2,8) }
    { const bool hi_ = (lane & 16) != 0;
      SHIP(0,1,16) }
    const float tot = v[0] + __shfl_xor(v[0], 32);
    const int idx = ((lane & 1) << 4) | ((lane & 2) << 2) | (lane & 4)
                  | ((lane & 8) >> 2) | ((lane & 16) >> 4);   // brev5(lane&31)
    if (lane < 32) red[wave][idx] = tot;
    __syncthreads();

    // ---- 24 threads: one tanh each (sum 8 waves now) ----
    if (tid < 24) {
        const int s = tid / 6;
        const int j = tid % 6;
        float ssq = 0.f, dot = 0.f;
#pragma unroll
        for (int w = 0; w < 8; ++w) {
            ssq += red[w][s * 7];
            dot += red[w][s * 7 + 1 + j];
        }
        const float rs = SQRT_D / fmaxf(sqrtf(ssq), 1e-12f);
        const float th = tanhf(dot * rs);
        asb[s][j] = (j < 5) ? (th * scale_alpha[0] + static_alpha[s * 5 + j])
                            : (th * scale_beta[0]  + static_beta[s]);
    }
    __syncthreads();

    // ---- Re-read x (L2-hit) for apply; M from asb overlaps the latency ----
    f32x4 y0 = *(const f32x4*)(xp);
    f32x4 y1 = *(const f32x4*)(xp + row_stride);
    f32x4 y2 = *(const f32x4*)(xp + 2 * row_stride);
    f32x4 y3 = *(const f32x4*)(xp + 3 * row_stride);

    // M[so][si] = beta[so]*alpha[si][0] + alpha[si][so+1] (broadcast LDS reads)
    float M[NS][NS];
#pragma unroll
    for (int so = 0; so < NS; ++so)
#pragma unroll
        for (int si = 0; si < NS; ++si)
            M[so][si] = __builtin_fmaf(asb[so][5], asb[si][0], asb[si][so + 1]);

    // ---- Apply: out[so][d] = sum_si M[so][si] * x[si][d] ----
#pragma unroll
    for (int so = 0; so < NS; ++so) {
        f32x4 o;
#pragma unroll
        for (int e = 0; e < 4; ++e)
            o[e] = M[so][0] * y0[e] + M[so][1] * y1[e]
                 + M[so][2] * y2[e] + M[so][3] * y3[e];
        __builtin_nontemporal_store(o, (f32x4*)(op + (size_t)so * row_stride));
    }
}

extern "C" void kernel_launch(void* const* d_in, const int* in_sizes, int n_in,
                              void* d_out, int out_size, void* d_ws, size_t ws_size,
                              hipStream_t stream) {
    const float* residuals    = (const float*)d_in[0];
    const float* gamma        = (const float*)d_in[1];
    const float* w_alpha      = (const float*)d_in[2];
    const float* scale_alpha  = (const float*)d_in[3];
    const float* static_alpha = (const float*)d_in[4];
    const float* w_beta       = (const float*)d_in[5];
    const float* scale_beta   = (const float*)d_in[6];
    const float* static_beta  = (const float*)d_in[7];
    float* out = (float*)d_out;

    const int grid = NB * NN;  // 8192 blocks, one per (b, n)
    hyperconn_kernel<<<grid, NTHREADS, 0, stream>>>(
        residuals, gamma, w_alpha, scale_alpha, static_alpha,
        w_beta, scale_beta, static_beta, out);
}

// Round 9
// 82.672 us; speedup vs baseline: 1.3066x; 1.3066x over previous
//
#include <hip/hip_runtime.h>
#include <math.h>

// Problem shape (fixed by the reference): B=4, S=4, N=2048, D=2048
#define NB 4
#define NS 4
#define NN 2048
#define ND 2048
#define NTHREADS 512
#define SQRT_D 45.254833995939045f   // sqrt(2048)

typedef float f32x4 __attribute__((ext_vector_type(4)));

// Compaction-butterfly ship, literal indices only (R3 lesson, R5/R7-proven).
#define SHIP(I, H, M_) {                                      \
    const float keep_ = hi_ ? v[(I)+(H)] : v[(I)];            \
    const float give_ = hi_ ? v[(I)] : v[(I)+(H)];            \
    v[(I)] = keep_ + __shfl_xor(give_, (M_)); }

// 512 threads, one f32x4 chunk per thread. (512,4): VGPR cap 128 so the
// ~90-reg demand (v[32] + live x + hoisted weights) fits WITHOUT demotion
// (R8 lesson: cap 64 demoted v[] to scratch, +70MB FETCH). x0..x3 stay
// live through the reduction -> apply needs no re-read, no LDS tile.
__global__ __launch_bounds__(NTHREADS, 4)
void hyperconn_kernel(const float* __restrict__ residuals,
                      const float* __restrict__ gamma,
                      const float* __restrict__ w_alpha,
                      const float* __restrict__ scale_alpha,
                      const float* __restrict__ static_alpha,
                      const float* __restrict__ w_beta,
                      const float* __restrict__ scale_beta,
                      const float* __restrict__ static_beta,
                      float* __restrict__ out)
{
    __shared__ float red[8][32];   // per-wave compacted sums (idx = brev5)
    __shared__ float asb[NS][6];   // [s][0..4]=alpha row, [s][5]=beta

    const int tid  = threadIdx.x;
    const int bn   = blockIdx.x;          // 0 .. NB*NN-1
    const int b    = bn >> 11;
    const int n    = bn & (NN - 1);
    const int wave = tid >> 6;
    const int lane = tid & 63;
    const int d    = tid << 2;            // one f32x4 chunk per thread

    const size_t row_stride = (size_t)NN * ND;
    const float* xp = residuals + (size_t)(b * NS) * row_stride + (size_t)n * ND + d;
    float*       op = out       + (size_t)(b * NS) * row_stride + (size_t)n * ND + d;

    // ---- Load x once; keep live until the apply phase ----
    f32x4 x0 = *(const f32x4*)(xp);
    f32x4 x1 = *(const f32x4*)(xp + row_stride);
    f32x4 x2 = *(const f32x4*)(xp + 2 * row_stride);
    f32x4 x3 = *(const f32x4*)(xp + 3 * row_stride);

    // ---- Dots in fp32 from registers ----
    // v[s*7]=ssq(x[s]); v[s*7+1+j]=dot(x[s], w_j*(1+g)); v[28..31] pad
    float v[32];
#pragma unroll
    for (int k = 0; k < 32; ++k) v[k] = 0.f;

    {
        f32x4 g4 = *(const f32x4*)(gamma + d);
#pragma unroll
        for (int e = 0; e < 4; ++e) {
            v[0]  = __builtin_fmaf(x0[e], x0[e], v[0]);
            v[7]  = __builtin_fmaf(x1[e], x1[e], v[7]);
            v[14] = __builtin_fmaf(x2[e], x2[e], v[14]);
            v[21] = __builtin_fmaf(x3[e], x3[e], v[21]);
        }
#pragma unroll
        for (int j = 0; j < 6; ++j) {
            const float* wsrc = (j < 5) ? (w_alpha + (size_t)j * ND + d)
                                        : (w_beta + d);
            f32x4 w4 = *(const f32x4*)wsrc;
            f32x4 wg = w4 + w4 * g4;       // w * (1 + gamma)
#pragma unroll
            for (int e = 0; e < 4; ++e) {
                v[1 + j]  = __builtin_fmaf(x0[e], wg[e], v[1 + j]);
                v[8 + j]  = __builtin_fmaf(x1[e], wg[e], v[8 + j]);
                v[15 + j] = __builtin_fmaf(x2[e], wg[e], v[15 + j]);
                v[22 + j] = __builtin_fmaf(x3[e], wg[e], v[22 + j]);
            }
        }
    }

    // ---- Compaction butterfly: 31 swizzles + 1 xor32 (R5/R7-proven) ----
    { const bool hi_ = (lane & 1) != 0;
      SHIP(0,16,1)  SHIP(1,16,1)  SHIP(2,16,1)  SHIP(3,16,1)
      SHIP(4,16,1)  SHIP(5,16,1)  SHIP(6,16,1)  SHIP(7,16,1)
      SHIP(8,16,1)  SHIP(9,16,1)  SHIP(10,16,1) SHIP(11,16,1)
      SHIP(12,16,1) SHIP(13,16,1) SHIP(14,16,1) SHIP(15,16,1) }
    { const bool hi_ = (lane & 2) != 0;
      SHIP(0,8,2) SHIP(1,8,2) SHIP(2,8,2) SHIP(3,8,2)
      SHIP(4,8,2) SHIP(5,8,2) SHIP(6,8,2) SHIP(7,8,2) }
    { const bool hi_ = (lane & 4) != 0;
      SHIP(0,4,4) SHIP(1,4,4) SHIP(2,4,4) SHIP(3,4,4) }
    { const bool hi_ = (lane & 8) != 0;
      SHIP(0,2,8) SHIP(1,2,8) }
    { const bool hi_ = (lane & 16) != 0;
      SHIP(0,1,16) }
    const float tot = v[0] + __shfl_xor(v[0], 32);
    const int idx = ((lane & 1) << 4) | ((lane & 2) << 2) | (lane & 4)
                  | ((lane & 8) >> 2) | ((lane & 16) >> 4);   // brev5(lane&31)
    if (lane < 32) red[wave][idx] = tot;
    __syncthreads();

    // ---- 24 threads: one tanh each (sum 8 waves) ----
    if (tid < 24) {
        const int s = tid / 6;
        const int j = tid % 6;
        float ssq = 0.f, dot = 0.f;
#pragma unroll
        for (int w = 0; w < 8; ++w) {
            ssq += red[w][s * 7];
            dot += red[w][s * 7 + 1 + j];
        }
        const float rs = SQRT_D / fmaxf(sqrtf(ssq), 1e-12f);
        const float th = tanhf(dot * rs);
        asb[s][j] = (j < 5) ? (th * scale_alpha[0] + static_alpha[s * 5 + j])
                            : (th * scale_beta[0]  + static_beta[s]);
    }
    __syncthreads();

    // ---- M[so][si] = beta[so]*alpha[si][0] + alpha[si][so+1] (broadcast reads) ----
    float M[NS][NS];
#pragma unroll
    for (int so = 0; so < NS; ++so)
#pragma unroll
        for (int si = 0; si < NS; ++si)
            M[so][si] = __builtin_fmaf(asb[so][5], asb[si][0], asb[si][so + 1]);

    // ---- Apply from the still-live x registers ----
#pragma unroll
    for (int so = 0; so < NS; ++so) {
        f32x4 o;
#pragma unroll
        for (int e = 0; e < 4; ++e)
            o[e] = M[so][0] * x0[e] + M[so][1] * x1[e]
                 + M[so][2] * x2[e] + M[so][3] * x3[e];
        __builtin_nontemporal_store(o, (f32x4*)(op + (size_t)so * row_stride));
    }
}

extern "C" void kernel_launch(void* const* d_in, const int* in_sizes, int n_in,
                              void* d_out, int out_size, void* d_ws, size_t ws_size,
                              hipStream_t stream) {
    const float* residuals    = (const float*)d_in[0];
    const float* gamma        = (const float*)d_in[1];
    const float* w_alpha      = (const float*)d_in[2];
    const float* scale_alpha  = (const float*)d_in[3];
    const float* static_alpha = (const float*)d_in[4];
    const float* w_beta       = (const float*)d_in[5];
    const float* scale_beta   = (const float*)d_in[6];
    const float* static_beta  = (const float*)d_in[7];
    float* out = (float*)d_out;

    const int grid = NB * NN;  // 8192 blocks, one per (b, n)
    hyperconn_kernel<<<grid, NTHREADS, 0, stream>>>(
        residuals, gamma, w_alpha, scale_alpha, static_alpha,
        w_beta, scale_beta, static_beta, out);
}